// Round 1
// baseline (751.219 us; speedup 1.0000x reference)
//
#include <hip/hip_runtime.h>
#include <stdint.h>
#include <stddef.h>

// ---------------------------------------------------------------------------
// Round 3: 256x256-tile pipelined GEMM template (BK=64, 8 waves, LDS dbuf,
// counted vmcnt(4) -- never drained in-loop, raw s_barrier, XOR-swizzled LDS
// so ds_read_b128 is bank-conflict-free, setprio around MFMA clusters).
// Used 4x:  Et = X_t*Wt^T+bt   (f16 out, scratch in d_out)
//           El = X_l*Wl^T+bl   (f16 out, scratch in d_out)
//           V-GEMM + fused softmax-merge epilogue -> Mg (f16, ws)
//           final projection (fp32 out + bias)
// ---------------------------------------------------------------------------

typedef _Float16 h8 __attribute__((ext_vector_type(8)));
typedef _Float16 h4 __attribute__((ext_vector_type(4)));
typedef float    f4 __attribute__((ext_vector_type(4)));

#define NROWS 32768

__device__ __forceinline__ void async_ld16(const void* g, void* s) {
  __builtin_amdgcn_global_load_lds(
      (const __attribute__((address_space(1))) uint32_t*)g,
      (__attribute__((address_space(3))) uint32_t*)s, 16, 0, 0);
}

#define MEMFENCE asm volatile("" ::: "memory")

// MODE: 0 = f16 out + bias (embed GEMMs)
//       1 = fused softmax-merge epilogue (V GEMM), reads Et/El, writes Mg f16
//       2 = fp32 out + bias (final projection)
// Block tile 256x256, K-tile 64, 8 waves (2 row x 4 col), per-wave 128x64.
// LDS 128 KB: 2 buffers x (A 32KB + B 32KB). Layout per buffer: element
// (row, k) at byte row*128 + ((k>>3) ^ (row&7))*16 + (k&7)*2  (XOR swizzle;
// staged via pre-swizzled per-lane GLOBAL source, linear LDS dest).
template<int NT, int MODE>
__launch_bounds__(512, 2)
__global__ void gemm256(const _Float16* __restrict__ A, int lda,
                        const _Float16* __restrict__ B, int ldb,
                        const float* __restrict__ bias,
                        const _Float16* __restrict__ Et,
                        const _Float16* __restrict__ El,
                        _Float16* __restrict__ C16,
                        float* __restrict__ C32) {
  __shared__ char smem[131072];

  // XCD-aware swizzle: 512 blocks, chunks of 64 consecutive row-blocks per
  // XCD slot (share the same B panel -> L2 hits). 512 % 8 == 0 -> bijective.
  const int b  = blockIdx.x;
  const int bp = ((b & 7) << 6) | (b >> 3);
  const int row0 = (bp & 127) << 8;   // 128 row-blocks
  const int col0 = (bp >> 7) << 8;    // 4 col-blocks

  const int tid  = threadIdx.x;
  const int w    = tid >> 6;
  const int lane = tid & 63;
  const int quad = lane >> 4;
  const int l16  = lane & 15;
  const int wr   = w >> 2;            // 0..1
  const int wc   = w & 3;             // 0..3
  const int m    = l16 & 7;

  // fragment-read byte offsets within a buffer (kf=0; kf=1 is ^64)
  const uint32_t sw = (uint32_t)((quad ^ m) << 4);
  const uint32_t a0 = (uint32_t)(((wr << 7) + l16) << 7) + sw;
  const uint32_t b0 = 32768u + (uint32_t)(((wc << 6) + l16) << 7) + sw;

  // staging: thread covers (row = h*128 + q*64 + w*8 + lane>>3, slot = lane&7)
  // global source slot pre-swizzled: slot ^ (row&7) = (lane&7) ^ (lane>>3)
  const int grow = (w << 3) + (lane >> 3);
  const int ss   = ((lane & 7) ^ (lane >> 3)) << 3;   // f16 units (x8)
  const _Float16* pA[2][2];
  const _Float16* pB[2][2];
#pragma unroll
  for (int h = 0; h < 2; ++h)
#pragma unroll
    for (int q = 0; q < 2; ++q) {
      pA[h][q] = A + (size_t)(row0 + h * 128 + q * 64 + grow) * (size_t)lda + ss;
      pB[h][q] = B + (size_t)(col0 + h * 128 + q * 64 + grow) * (size_t)ldb + ss;
    }

  f4 acc[8][4];
  const f4 z = {0.f, 0.f, 0.f, 0.f};
#pragma unroll
  for (int i = 0; i < 8; ++i)
#pragma unroll
    for (int j = 0; j < 4; ++j) acc[i][j] = z;

  char* const sm = smem;
  const int woff = w << 10;   // per-wave 1KB slice of each 8KB stage region

  // prologue: stage K-tile 0 into buffer 0 (A then B: 8 loads in flight)
#pragma unroll
  for (int h = 0; h < 2; ++h)
#pragma unroll
    for (int q = 0; q < 2; ++q)
      async_ld16(pA[h][q], sm + h * 16384 + q * 8192 + woff);
#pragma unroll
  for (int h = 0; h < 2; ++h)
#pragma unroll
    for (int q = 0; q < 2; ++q)
      async_ld16(pB[h][q], sm + 32768 + h * 16384 + q * 8192 + woff);

  uint32_t cur = 0;
  for (int t = 0; t < NT; ++t) {
    const int tn = (t + 1 < NT) ? (t + 1) : t;     // last iter: harmless dummy re-stage
    const uint32_t nxt = cur ^ 65536u;

    // ---- phase 1: stage A(t+1) | publish tile t | MFMA k-frag 0 ----
#pragma unroll
    for (int h = 0; h < 2; ++h)
#pragma unroll
      for (int q = 0; q < 2; ++q)
        async_ld16(pA[h][q] + tn * 64, sm + nxt + h * 16384 + q * 8192 + woff);
    // outstanding: A(t)4 + B(t)4 + A(t+1)4 -> wait 8 oldest (tile t) landed
    asm volatile("s_waitcnt vmcnt(4)" ::: "memory");
    __builtin_amdgcn_s_barrier();
    MEMFENCE;
    {
      const uint32_t A0 = cur + a0, B0 = cur + b0;
      h8 af[8], bf[4];
#pragma unroll
      for (int i = 0; i < 8; ++i) af[i] = *(const h8*)(sm + A0 + i * 2048);
#pragma unroll
      for (int j = 0; j < 4; ++j) bf[j] = *(const h8*)(sm + B0 + j * 2048);
      __builtin_amdgcn_s_setprio(1);
#pragma unroll
      for (int i = 0; i < 8; ++i)
#pragma unroll
        for (int j = 0; j < 4; ++j)
          acc[i][j] = __builtin_amdgcn_mfma_f32_16x16x32_f16(af[i], bf[j],
                                                             acc[i][j], 0, 0, 0);
      __builtin_amdgcn_s_setprio(0);
    }
    MEMFENCE;
    __builtin_amdgcn_s_barrier();
    MEMFENCE;

    // ---- phase 2: stage B(t+1) | MFMA k-frag 1 (tile t already published) ----
#pragma unroll
    for (int h = 0; h < 2; ++h)
#pragma unroll
      for (int q = 0; q < 2; ++q)
        async_ld16(pB[h][q] + tn * 64, sm + nxt + 32768 + h * 16384 + q * 8192 + woff);
    {
      const uint32_t A1 = (cur + a0) ^ 64u, B1 = (cur + b0) ^ 64u;
      h8 af[8], bf[4];
#pragma unroll
      for (int i = 0; i < 8; ++i) af[i] = *(const h8*)(sm + A1 + i * 2048);
#pragma unroll
      for (int j = 0; j < 4; ++j) bf[j] = *(const h8*)(sm + B1 + j * 2048);
      __builtin_amdgcn_s_setprio(1);
#pragma unroll
      for (int i = 0; i < 8; ++i)
#pragma unroll
        for (int j = 0; j < 4; ++j)
          acc[i][j] = __builtin_amdgcn_mfma_f32_16x16x32_f16(af[i], bf[j],
                                                             acc[i][j], 0, 0, 0);
      __builtin_amdgcn_s_setprio(0);
    }
    MEMFENCE;
    __builtin_amdgcn_s_barrier();
    MEMFENCE;
    cur = nxt;
  }
  asm volatile("s_waitcnt vmcnt(0)" ::: "memory");  // drain dummy stages

  // ---- epilogue ----
  // C layout per MFMA frag: col = l16, row = quad*4 + r
  const int cbase  = col0 + (wc << 6);
  const int rbase0 = row0 + (wr << 7) + (quad << 2);

  if constexpr (MODE == 0) {
    float bj[4];
#pragma unroll
    for (int j = 0; j < 4; ++j) bj[j] = bias[cbase + j * 16 + l16];
#pragma unroll
    for (int i = 0; i < 8; ++i)
#pragma unroll
      for (int j = 0; j < 4; ++j) {
        const size_t co = (size_t)(cbase + j * 16 + l16);
#pragma unroll
        for (int r = 0; r < 4; ++r)
          C16[(size_t)(rbase0 + i * 16 + r) * 1024 + co] =
              (_Float16)(acc[i][j][r] + bj[j]);
      }
  } else if constexpr (MODE == 2) {
    float bj[4];
#pragma unroll
    for (int j = 0; j < 4; ++j) bj[j] = bias[cbase + j * 16 + l16];
#pragma unroll
    for (int i = 0; i < 8; ++i)
#pragma unroll
      for (int j = 0; j < 4; ++j) {
        const size_t co = (size_t)(cbase + j * 16 + l16);
#pragma unroll
        for (int r = 0; r < 4; ++r)
          C32[(size_t)(rbase0 + i * 16 + r) * 1024 + co] = acc[i][j][r] + bj[j];
      }
  } else {
    // fused softmax-merge: wave's 64 cols == exactly one head group.
    float bvj[4];
#pragma unroll
    for (int j = 0; j < 4; ++j) bvj[j] = bias[cbase + j * 16 + l16];
#pragma unroll
    for (int i = 0; i < 8; ++i) {
      float pv[4][4];
      float s[4] = {0.f, 0.f, 0.f, 0.f};
      const int rb = rbase0 + i * 16;
#pragma unroll
      for (int j = 0; j < 4; ++j) {
        const size_t co = (size_t)(cbase + j * 16 + l16);
#pragma unroll
        for (int r = 0; r < 4; ++r) {
          const size_t off = (size_t)(rb + r) * 1024 + co;
          const float tv = (float)Et[off];   // bias already folded in
          const float lv = (float)El[off];
          const float p  = __expf(tv * lv);
          pv[j][r] = p * (acc[i][j][r] + bvj[j]);
          s[r] += p;
        }
      }
#pragma unroll
      for (int r = 0; r < 4; ++r) {
        s[r] += __shfl_xor(s[r], 1);
        s[r] += __shfl_xor(s[r], 2);
        s[r] += __shfl_xor(s[r], 4);
        s[r] += __shfl_xor(s[r], 8);
        s[r] = 1.0f / s[r];
      }
#pragma unroll
      for (int j = 0; j < 4; ++j) {
        const size_t co = (size_t)(cbase + j * 16 + l16);
#pragma unroll
        for (int r = 0; r < 4; ++r)
          C16[(size_t)(rb + r) * 1024 + co] = (_Float16)(pv[j][r] * s[r]);
      }
    }
  }
}

// ---------------------------------------------------------------------------
// Prep kernels (unchanged from round 2)
// ---------------------------------------------------------------------------
__global__ void cvt_inputs(const float4* __restrict__ t,
                           const float4* __restrict__ l,
                           h4* __restrict__ X) {
  const size_t idx = (size_t)blockIdx.x * 256 + threadIdx.x;  // N*1024/4
  const size_t n  = idx >> 8;
  const size_t k4 = idx & 255;
  const float4 a = t[idx];
  const float4 b = l[idx];
  h4 ha, hb;
  ha[0] = (_Float16)a.x; ha[1] = (_Float16)a.y;
  ha[2] = (_Float16)a.z; ha[3] = (_Float16)a.w;
  hb[0] = (_Float16)b.x; hb[1] = (_Float16)b.y;
  hb[2] = (_Float16)b.z; hb[3] = (_Float16)b.w;
  X[n * 512 + k4]       = ha;
  X[n * 512 + 256 + k4] = hb;
}

__global__ void cvt_flat(const float4* __restrict__ W, h4* __restrict__ Wp) {
  const int idx = blockIdx.x * 256 + threadIdx.x;
  const float4 v = W[idx];
  h4 hv;
  hv[0] = (_Float16)v.x; hv[1] = (_Float16)v.y;
  hv[2] = (_Float16)v.z; hv[3] = (_Float16)v.w;
  Wp[idx] = hv;
}

// Wo with K-dim permuted to match Mg's column order c = h*64+o
__global__ void cvt_wo_perm(const float* __restrict__ Wo,
                            _Float16* __restrict__ Wp) {
  const int idx = blockIdx.x * 256 + threadIdx.x;  // 1M
  const int j = idx >> 10, c = idx & 1023;
  const int k = (c & 63) * 16 + (c >> 6);
  Wp[idx] = (_Float16)Wo[j * 1024 + k];
}

// ---------------------------------------------------------------------------
// Launch. ws (~212 MB):  X16 134MB | Wt16 2MB | Wl16 2MB | Wv16 4MB |
//                        Wo16 2MB  | Mg 67MB
// d_out doubles as f16 scratch for Et/El (2 x 67MB = exactly out_size);
// they are consumed by the V kernel before the final GEMM overwrites d_out.
// ---------------------------------------------------------------------------
extern "C" void kernel_launch(void* const* d_in, const int* in_sizes, int n_in,
                              void* d_out, int out_size, void* d_ws, size_t ws_size,
                              hipStream_t stream) {
  const float* t_inp = (const float*)d_in[0];
  const float* l_inp = (const float*)d_in[1];
  const float* Wt = (const float*)d_in[2];
  const float* bt = (const float*)d_in[3];
  const float* Wl = (const float*)d_in[4];
  const float* bl = (const float*)d_in[5];
  const float* Wv = (const float*)d_in[6];
  const float* bv = (const float*)d_in[7];
  const float* Wo = (const float*)d_in[8];
  const float* bo = (const float*)d_in[9];
  float* out = (float*)d_out;

  char* ws = (char*)d_ws;
  _Float16* X16  = (_Float16*)ws;
  _Float16* Wt16 = (_Float16*)(ws + 134217728ull);
  _Float16* Wl16 = Wt16 + 1024 * 1024;
  _Float16* Wv16 = Wl16 + 1024 * 1024;
  _Float16* Wo16 = Wv16 + 1024 * 2048;
  _Float16* Mg   = Wo16 + 1024 * 1024;

  _Float16* Et16 = (_Float16*)d_out;            // scratch: 67MB
  _Float16* El16 = Et16 + (size_t)NROWS * 1024; // scratch: 67MB

  cvt_inputs<<<dim3(32768), dim3(256), 0, stream>>>(
      (const float4*)t_inp, (const float4*)l_inp, (h4*)X16);
  cvt_flat<<<dim3(1024), dim3(256), 0, stream>>>((const float4*)Wt, (h4*)Wt16);
  cvt_flat<<<dim3(1024), dim3(256), 0, stream>>>((const float4*)Wl, (h4*)Wl16);
  cvt_flat<<<dim3(2048), dim3(256), 0, stream>>>((const float4*)Wv, (h4*)Wv16);
  cvt_wo_perm<<<dim3(4096), dim3(256), 0, stream>>>(Wo, Wo16);

  // Et = X_t * Wt^T + bt   (f16, into d_out scratch)
  gemm256<16, 0><<<dim3(512), dim3(512), 0, stream>>>(
      X16, 2048, Wt16, 1024, bt, nullptr, nullptr, Et16, nullptr);
  // El = X_l * Wl^T + bl
  gemm256<16, 0><<<dim3(512), dim3(512), 0, stream>>>(
      X16 + 1024, 2048, Wl16, 1024, bl, nullptr, nullptr, El16, nullptr);
  // V GEMM + fused softmax-merge -> Mg
  gemm256<32, 1><<<dim3(512), dim3(512), 0, stream>>>(
      X16, 2048, Wv16, 2048, bv, Et16, El16, Mg, nullptr);
  // final projection (fp32 out + bias)
  gemm256<16, 2><<<dim3(512), dim3(512), 0, stream>>>(
      Mg, 1024, Wo16, 1024, bo, nullptr, nullptr, nullptr, out);
}